// Round 19
// baseline (53.382 us; speedup 1.0000x reference)
//
#include <hip/hip_runtime.h>

#define Bn 1024
#define Dn 32
#define Mn 8
#define Rn 4096
#define Cn 32
#define Kn 409     // int(0.1 * 4096)
#define NTH 512
#define NBIN 1024
#define CCAP 256   // candidate cap (9 bins at the boundary)
#define MARG 4     // bf16 key err <= |key|*2^-9 <= 0.234 at clamp; region +-4*0.117 = 0.47 covers 2x

typedef unsigned int u32;
typedef unsigned short u16;
typedef short bf16x8 __attribute__((ext_vector_type(8)));
typedef float f32x4 __attribute__((ext_vector_type(4)));

// Histogram bin of an f32 key; monotone non-decreasing. Keys in (-120, 0], clamped.
__device__ __forceinline__ int binof(float kf) {
    int b = (int)floorf(kf * (float)(NBIN / 120.0) + (float)NBIN);
    return b < 0 ? 0 : (b > NBIN - 1 ? NBIN - 1 : b);
}

// f32 -> bf16 round-to-nearest-even
__device__ __forceinline__ u16 f2bf(float v) {
    u32 b = __float_as_uint(v);
    b += 0x7fffu + ((b >> 16) & 1u);
    return (u16)(b >> 16);
}

__device__ __forceinline__ uint4 onehot4(int v) {
    uint4 o;
    o.x = (v == 0 ? 0x3F80u : 0u) | (v == 1 ? (0x3F80u << 16) : 0u);
    o.y = (v == 2 ? 0x3F80u : 0u) | (v == 3 ? (0x3F80u << 16) : 0u);
    o.z = (v == 4 ? 0x3F80u : 0u) | (v == 5 ? (0x3F80u << 16) : 0u);
    o.w = (v == 6 ? 0x3F80u : 0u) | (v == 7 ? (0x3F80u << 16) : 0u);
    return o;
}

// keys GEMM (R16 body + bf16-key epilogue): 32(M)x128(N)/block, 1024 x 512 thr.
// Keys now stored bf16 (binning-only precision) -> 8MB instead of 16MB.
__global__ __launch_bounds__(NTH, 8) void key_gemm_kernel(
    const float* __restrict__ x, const float* __restrict__ centers,
    const float* __restrict__ widths, const float* __restrict__ cons,
    const int* __restrict__ rules,
    float* __restrict__ cons_sum, u16* __restrict__ keys)
{
    __shared__ float s_cen[256];
    __shared__ float s_inv[256];
    __shared__ u16 sAh[32 * 32];
    __shared__ u16 sAl[32 * 32];
    __shared__ u16 sB[128 * 32];   // k-loop: B tile; epilogue: bf16 C staging [32][128]

    const int blk = blockIdx.x;
    const int t = threadIdx.x;
    const int lane = t & 63;
    const int w = t >> 6;
    const int m0 = (blk >> 5) * 32;
    const int n0 = (blk & 31) * 128;
    const int wr = w >> 2;
    const int wc = w & 3;

    if (t < 256) {
        const float ww = widths[t];
        s_cen[t] = centers[t];
        s_inv[t] = 0.5f / (ww * ww);
    }

    f32x4 acc0 = (f32x4){0.f, 0.f, 0.f, 0.f};
    f32x4 acc1 = (f32x4){0.f, 0.f, 0.f, 0.f};

    const int brow = t >> 2;
    const int aj = t & 3;
    const int cidx = blk * 128 + (t & 127);
    const float* cp = cons + (size_t)(cidx >> 5) * ((Dn + 1) * Cn) + (cidx & 31);
    float csum = 0.f;
    __syncthreads();

#pragma unroll
    for (int ki = 0; ki < 8; ++ki) {
        const int d0 = ki * 4;
        {
            const int v = rules[(size_t)(n0 + brow) * Dn + d0 + aj];
            *(uint4*)(sB + brow * 32 + aj * 8) = onehot4(v);
        }
        if (t < 128) {
            const int arow = t >> 2;
            const float xv = x[(size_t)(m0 + arow) * Dn + d0 + aj];
            const int dm0 = (d0 + aj) * 8;
            u16 h[8], l[8];
#pragma unroll
            for (int m = 0; m < 8; ++m) {
                const float dx = xv - s_cen[dm0 + m];
                const float e = -(dx * dx) * s_inv[dm0 + m];
                const u16 hb = f2bf(e);
                h[m] = hb;
                l[m] = f2bf(e - __uint_as_float((u32)hb << 16));
            }
            *(uint4*)(sAh + arow * 32 + aj * 8) =
                make_uint4((u32)h[0] | ((u32)h[1] << 16), (u32)h[2] | ((u32)h[3] << 16),
                           (u32)h[4] | ((u32)h[5] << 16), (u32)h[6] | ((u32)h[7] << 16));
            *(uint4*)(sAl + arow * 32 + aj * 8) =
                make_uint4((u32)l[0] | ((u32)l[1] << 16), (u32)l[2] | ((u32)l[3] << 16),
                           (u32)l[4] | ((u32)l[5] << 16), (u32)l[6] | ((u32)l[7] << 16));
#pragma unroll
            for (int q = 0; q < 4; ++q) csum += cp[(ki * 4 + q) * Cn];
        }
        __syncthreads();
        bf16x8 ah = *(const bf16x8*)(sAh + ((wr * 16 + (lane & 15)) * 32 + (lane >> 4) * 8));
        bf16x8 al = *(const bf16x8*)(sAl + ((wr * 16 + (lane & 15)) * 32 + (lane >> 4) * 8));
        bf16x8 b0 = *(const bf16x8*)(sB + ((wc * 32 + (lane & 15)) * 32 + (lane >> 4) * 8));
        bf16x8 b1 = *(const bf16x8*)(sB + ((wc * 32 + 16 + (lane & 15)) * 32 + (lane >> 4) * 8));
        acc0 = __builtin_amdgcn_mfma_f32_16x16x32_bf16(ah, b0, acc0, 0, 0, 0);
        acc0 = __builtin_amdgcn_mfma_f32_16x16x32_bf16(al, b0, acc0, 0, 0, 0);
        acc1 = __builtin_amdgcn_mfma_f32_16x16x32_bf16(ah, b1, acc1, 0, 0, 0);
        acc1 = __builtin_amdgcn_mfma_f32_16x16x32_bf16(al, b1, acc1, 0, 0, 0);
        __syncthreads();
    }
    if (t < 128) {
        csum += cp[Dn * Cn];
        cons_sum[cidx] = csum;
    }
    // epilogue: stage C as bf16 in sB [32][128], then coalesced uint4 stores.
    // C/D mapping: col=lane&15, row=(lane>>4)*4+reg [m89-verified]
    {
        const int cr = (lane >> 4) * 4;
        const int cc = lane & 15;
#pragma unroll
        for (int reg = 0; reg < 4; ++reg) {
            const int row = wr * 16 + cr + reg;
            sB[row * 128 + wc * 32 + cc] = f2bf(acc0[reg]);
            sB[row * 128 + wc * 32 + 16 + cc] = f2bf(acc1[reg]);
        }
        __syncthreads();
        const int row = t >> 4;
        const int col0 = (t & 15) * 8;
        *(uint4*)(keys + (size_t)(m0 + row) * Rn + n0 + col0) = *(const uint4*)(sB + row * 128 + col0);
    }
}

// select v3: one row/block, (512,8). bf16 keys (1 uint4 load = this thread's
// 8 contiguous rules 8t..8t+7) drive binning with a +-MARG region; boundary
// decided by exact f64 rescore + index tie-break (unchanged). Values for the
// 409 selected rules recomputed convergently in f64 from the LDS table.
__global__ __launch_bounds__(NTH, 8) void select_kernel(
    const float* __restrict__ x,
    const float* __restrict__ centers,
    const float* __restrict__ widths,
    const u16* __restrict__ keys,
    const int* __restrict__ rules,
    const float* __restrict__ cons_sum,
    float* __restrict__ out_rule,
    float* __restrict__ out_norm,
    float* __restrict__ out_mask)
{
    __shared__ float  s_x[Dn];
    __shared__ double s_e[256];            // 2KB f64 table (rescore + values)
    __shared__ u32    s_hist[NBIN + 2];    // 4KB; becomes suffix array in place
    __shared__ u32    s_selmask[Rn / 32];  // 0.5KB selection bitmap
    __shared__ int    s_wtot[8];
    __shared__ float  s_wsum[8];
    __shared__ int    s_wpre[8];
    __shared__ int    s_cidx[CCAP];        // 1KB
    __shared__ double s_cval[CCAP];        // 2KB
    __shared__ int    s_selidx[Kn + 8];    // 1.6KB
    __shared__ float  s_selv[Kn + 8];      // 1.6KB
    __shared__ float  s_red[NTH];          // 2KB
    __shared__ int    s_bb, s_ccnt;

    const int t = threadIdx.x;
    const int lane = t & 63;
    const int w = t >> 6;
    const int b = blockIdx.x;

    // one uint4 = this thread's 8 bf16 keys (rules 8t..8t+7)
    const uint4 kv = ((const uint4*)(keys + (size_t)b * Rn))[t];
    float k[8];
    k[0] = __uint_as_float(kv.x << 16); k[1] = __uint_as_float(kv.x & 0xFFFF0000u);
    k[2] = __uint_as_float(kv.y << 16); k[3] = __uint_as_float(kv.y & 0xFFFF0000u);
    k[4] = __uint_as_float(kv.z << 16); k[5] = __uint_as_float(kv.z & 0xFFFF0000u);
    k[6] = __uint_as_float(kv.w << 16); k[7] = __uint_as_float(kv.w & 0xFFFF0000u);

    if (t < Dn) s_x[t] = x[b * Dn + t];
    if (t == 0) { s_ccnt = 0; s_hist[NBIN] = 0u; s_hist[NBIN + 1] = 0u; }
    s_hist[t] = 0u;
    s_hist[t + NTH] = 0u;
    if (t < Rn / 32) s_selmask[t] = 0u;
    __syncthreads();

    // f64 single-dim table (bit-exact same math as all passing rounds)
    if (t < 256) {
        const int d = t >> 3;
        const double dx = (double)s_x[d] - (double)centers[t];
        const double ww = (double)widths[t];
        s_e[t] = -(dx * dx) / (2.0 * (ww * ww));
    }
    // histogram
#pragma unroll
    for (int j = 0; j < 8; ++j) atomicAdd(&s_hist[binof(k[j])], 1u);
    __syncthreads();

    // suffix scan over 1024 bins, in place: s_hist[kk] := #keys in bins >= kk
    const int h0 = (int)s_hist[2 * t];
    const int h1 = (int)s_hist[2 * t + 1];
    const int loc = h0 + h1;
    int S = loc;
#pragma unroll
    for (int off = 1; off < 64; off <<= 1) {
        const int vv = __shfl(S, lane + off < 64 ? lane + off : lane);
        if (lane + off < 64) S += vv;
    }
    if (lane == 0) s_wtot[w] = S;
    __syncthreads();
    int wsuf = 0;
#pragma unroll
    for (int ww = 0; ww < 8; ++ww) wsuf += (ww > w) ? s_wtot[ww] : 0;
    const int full = S + wsuf;
    s_hist[2 * t] = (u32)full;
    s_hist[2 * t + 1] = (u32)(full - h0);
    if (full - loc < Kn && full >= Kn) {
        s_bb = (full - h0 >= Kn) ? (2 * t + 1) : (2 * t);
    }
    __syncthreads();
    const int bb = s_bb;
    const int hi = (bb + MARG > NBIN - 1) ? NBIN - 1 : bb + MARG;
    const int lo = (bb - MARG < 0) ? 0 : bb - MARG;
    const int Acnt = (int)s_hist[hi + 1];   // keys in bins > hi: certainly top-K
    const int want_in = Kn - Acnt;

    // candidate append
#pragma unroll
    for (int j = 0; j < 8; ++j) {
        const int bn = binof(k[j]);
        if (bn >= lo && bn <= hi) {
            const int pos = atomicAdd(&s_ccnt, 1);
            if (pos < CCAP) s_cidx[pos] = 8 * t + j;
        }
    }
    __syncthreads();
    const int cnt = s_ccnt < CCAP ? s_ccnt : CCAP;
    // convergent exact rescore (ascending d = bit-exact order vs prior rounds)
    if (t < cnt) {
        const int* rp = rules + s_cidx[t] * Dn;
        double s = 0.0;
#pragma unroll
        for (int d = 0; d < Dn; ++d) s += s_e[d * 8 + rp[d]];
        s_cval[t] = s;
    }
    __syncthreads();
    if (t < cnt) {
        const double mv = s_cval[t];
        const int mi = s_cidx[t];
        int rank = 0;
        for (int j = 0; j < cnt; ++j) {
            const double ov = s_cval[j];
            const int oi = s_cidx[j];
            rank += ((ov > mv) || (ov == mv && oi < mi)) ? 1 : 0;
        }
        if (rank < want_in) atomicOr(&s_selmask[mi >> 5], 1u << (mi & 31));
    }
    __syncthreads();

    // selection decision (bins + bitmap only; values come later)
    u32 selbits = 0u;
    int cnt_sel = 0;
#pragma unroll
    for (int j = 0; j < 8; ++j) {
        const int bn = binof(k[j]);
        const int r = 8 * t + j;
        bool sel = (bn > hi);
        if (!sel && bn >= lo) sel = (s_selmask[r >> 5] >> (r & 31)) & 1u;
        if (sel) { selbits |= (1u << j); ++cnt_sel; }
    }
    // compaction prefix
    int p = cnt_sel;
#pragma unroll
    for (int off = 1; off < 64; off <<= 1) {
        const int u = __shfl(p, lane >= off ? lane - off : lane);
        if (lane >= off) p += u;
    }
    if (lane == 63) s_wpre[w] = p;
    __syncthreads();
    int base = 0, nsel = 0;
#pragma unroll
    for (int ww = 0; ww < 8; ++ww) { base += (ww < w) ? s_wpre[ww] : 0; nsel += s_wpre[ww]; }
    int pos = base + (p - cnt_sel);
    const int mypos0 = pos;
#pragma unroll
    for (int j = 0; j < 8; ++j) {
        if ((selbits >> j) & 1u) s_selidx[pos++] = 8 * t + j;
    }
    __syncthreads();

    // value pass: exact f64 sum -> expf for the selected rules (convergent)
    if (t < nsel) {
        const int* rp = rules + s_selidx[t] * Dn;
        double s = 0.0;
#pragma unroll
        for (int d = 0; d < Dn; ++d) s += s_e[d * 8 + rp[d]];
        s_selv[t] = expf((float)s);
    }
    __syncthreads();
    // denominator
    float lsum = (t < nsel) ? s_selv[t] : 0.f;
#pragma unroll
    for (int off = 32; off >= 1; off >>= 1) lsum += __shfl_xor(lsum, off);
    if (lane == 0) s_wsum[w] = lsum;
    __syncthreads();
    float denom = 1e-9f;
#pragma unroll
    for (int ww = 0; ww < 8; ++ww) denom += s_wsum[ww];
    const float rinv = 1.0f / denom;

    // norm/mask writes: thread t owns rules 8t..8t+7 (contiguous, coalesced)
    {
        f32x4 nv0, nv1, mk0, mk1;
        int rp2 = mypos0;
        float v[8];
#pragma unroll
        for (int j = 0; j < 8; ++j) {
            v[j] = ((selbits >> j) & 1u) ? s_selv[rp2++] * rinv : 0.f;
        }
        nv0.x = v[0]; nv0.y = v[1]; nv0.z = v[2]; nv0.w = v[3];
        nv1.x = v[4]; nv1.y = v[5]; nv1.z = v[6]; nv1.w = v[7];
        mk0.x = (selbits & 1u) ? 1.f : 0.f;  mk0.y = (selbits & 2u) ? 1.f : 0.f;
        mk0.z = (selbits & 4u) ? 1.f : 0.f;  mk0.w = (selbits & 8u) ? 1.f : 0.f;
        mk1.x = (selbits & 16u) ? 1.f : 0.f; mk1.y = (selbits & 32u) ? 1.f : 0.f;
        mk1.z = (selbits & 64u) ? 1.f : 0.f; mk1.w = (selbits & 128u) ? 1.f : 0.f;
        f32x4* onorm = (f32x4*)(out_norm + (size_t)b * Rn);
        f32x4* omask = (f32x4*)(out_mask + (size_t)b * Rn);
        __builtin_nontemporal_store(nv0, &onorm[2 * t]);
        __builtin_nontemporal_store(nv1, &onorm[2 * t + 1]);
        __builtin_nontemporal_store(mk0, &omask[2 * t]);
        __builtin_nontemporal_store(mk1, &omask[2 * t + 1]);
    }
    __syncthreads();

    // sparse matvec over compacted list (s_selv holds raw f; scale by rinv at end)
    const int g = t >> 5;
    const int c = t & 31;
    float acc = 0.f;
    for (int i = g; i < nsel; i += 16) {
        acc += s_selv[i] * cons_sum[s_selidx[i] * Cn + c];
    }
    s_red[t] = acc;
    __syncthreads();
    if (t < Cn) {
        float ss = 0.f;
#pragma unroll
        for (int gg = 0; gg < 16; ++gg) ss += s_red[gg * 32 + t];
        float xs = 1.f;
#pragma unroll
        for (int d = 0; d < Dn; ++d) xs += s_x[d];
        __builtin_nontemporal_store(xs * ss * rinv, &out_rule[(size_t)b * Cn + t]);
    }
}

extern "C" void kernel_launch(void* const* d_in, const int* in_sizes, int n_in,
                              void* d_out, int out_size, void* d_ws, size_t ws_size,
                              hipStream_t stream) {
    (void)in_sizes; (void)n_in; (void)out_size; (void)ws_size;
    const float* x = (const float*)d_in[0];
    const float* centers = (const float*)d_in[1];
    const float* widths = (const float*)d_in[2];
    const float* consequents = (const float*)d_in[3];
    const int* rules = (const int*)d_in[4];

    float* out_rule = (float*)d_out;                       // B*C
    float* out_norm = out_rule + (size_t)Bn * Cn;          // B*R
    float* out_mask = out_norm + (size_t)Bn * Rn;          // B*R

    char* wsb = (char*)d_ws;
    float* cons_sum = (float*)wsb;                         // 512KB @ 0
    u16*   keys = (u16*)(wsb + (512 << 10));               // 8MB   @ 512K

    key_gemm_kernel<<<1024, NTH, 0, stream>>>(x, centers, widths, consequents, rules,
                                              cons_sum, keys);
    select_kernel<<<Bn, NTH, 0, stream>>>(x, centers, widths, keys, rules, cons_sum,
                                          out_rule, out_norm, out_mask);
}

// Round 20
// 42.596 us; speedup vs baseline: 1.2532x; 1.2532x over previous
//
#include <hip/hip_runtime.h>

#define Bn 1024
#define Dn 32
#define Mn 8
#define Rn 4096
#define Cn 32
#define Kn 409     // int(0.1 * 4096)
#define NTH 512
#define NBIN 1024
#define CCAP 256   // candidate cap (3 bins at the boundary)

typedef unsigned int u32;
typedef unsigned short u16;
typedef short bf16x8 __attribute__((ext_vector_type(8)));
typedef float f32x4 __attribute__((ext_vector_type(4)));

// Histogram bin of an f32 key; monotone non-decreasing. Keys in (-120, 0], clamped.
__device__ __forceinline__ int binof(float kf) {
    int b = (int)floorf(kf * (float)(NBIN / 120.0) + (float)NBIN);
    return b < 0 ? 0 : (b > NBIN - 1 ? NBIN - 1 : b);
}

// f32 -> bf16 round-to-nearest-even
__device__ __forceinline__ u16 f2bf(float v) {
    u32 b = __float_as_uint(v);
    b += 0x7fffu + ((b >> 16) & 1u);
    return (u16)(b >> 16);
}

// Fused prep (1152 blocks):
//  [0,512):     cons_sum[r][c] = sum_k consequents[r][k][c]
//  [512,1024):  S one-hot, 8 rules/block, 1 uint4 (8 bf16) per thread, coalesced
//  [1024,1152): E_hi/E_lo split, 8 rows/block, 1 uint4 each per thread
__global__ __launch_bounds__(256) void prep_kernel(
    const float* __restrict__ x, const float* __restrict__ centers,
    const float* __restrict__ widths, const float* __restrict__ cons,
    const int* __restrict__ rules,
    float* __restrict__ cons_out,
    uint4* __restrict__ S4, uint4* __restrict__ Ehi4, uint4* __restrict__ Elo4)
{
    const int blk = blockIdx.x;
    const int t = threadIdx.x;
    if (blk < 512) {
        const int idx = blk * 256 + t;
        const int r = idx >> 5, c = idx & 31;
        const float* p = cons + (size_t)r * (Dn + 1) * Cn + c;
        float s = 0.0f;
#pragma unroll
        for (int k = 0; k < Dn + 1; ++k) s += p[(size_t)k * Cn];
        cons_out[idx] = s;
    } else if (blk < 1024) {
        const int r = (blk - 512) * 8 + (t >> 5);
        const int d = t & 31;
        const int v = rules[r * Dn + d];
        uint4 o;
        o.x = (v == 0 ? 0x3F80u : 0u) | (v == 1 ? (0x3F80u << 16) : 0u);
        o.y = (v == 2 ? 0x3F80u : 0u) | (v == 3 ? (0x3F80u << 16) : 0u);
        o.z = (v == 4 ? 0x3F80u : 0u) | (v == 5 ? (0x3F80u << 16) : 0u);
        o.w = (v == 6 ? 0x3F80u : 0u) | (v == 7 ? (0x3F80u << 16) : 0u);
        S4[r * 32 + d] = o;
    } else {
        const int row = (blk - 1024) * 8 + (t >> 5);
        const int d = t & 31;
        const float xv = x[row * Dn + d];
        u16 h[8], l[8];
#pragma unroll
        for (int m = 0; m < 8; ++m) {
            const float c = centers[d * 8 + m];
            const float w = widths[d * 8 + m];
            const float dx = xv - c;
            const float e = -(dx * dx) / (2.f * w * w);
            const u16 hb = f2bf(e);
            h[m] = hb;
            l[m] = f2bf(e - __uint_as_float((u32)hb << 16));   // exact residual, bf16-rounded
        }
        Ehi4[row * 32 + d] = make_uint4((u32)h[0] | ((u32)h[1] << 16), (u32)h[2] | ((u32)h[3] << 16),
                                        (u32)h[4] | ((u32)h[5] << 16), (u32)h[6] | ((u32)h[7] << 16));
        Elo4[row * 32 + d] = make_uint4((u32)l[0] | ((u32)l[1] << 16), (u32)l[2] | ((u32)l[3] << 16),
                                        (u32)l[4] | ((u32)l[5] << 16), (u32)l[6] | ((u32)l[7] << 16));
    }
}

// keys[b][r] = sum_dm (Ehi+Elo)[b][dm] * S[r][dm] — split-bf16 GEMM.
// 64(M)x128(N), BK=32 -> 512 blocks (2/CU), LDS 32KB. Verified fragment math;
// wave grid 2x2, each wave 32x64 (acc[2][4]).
__global__ __launch_bounds__(256) void key_gemm_kernel(
    const u16* __restrict__ Ehi, const u16* __restrict__ Elo,
    const u16* __restrict__ S, float* __restrict__ keys)
{
    __shared__ u16 sAh[2][64 * 32];    // 8KB
    __shared__ u16 sAl[2][64 * 32];    // 8KB
    __shared__ u16 sB[2][128 * 32];    // 16KB
    const int t = threadIdx.x;
    const int lane = t & 63;
    const int w = t >> 6;
    const int wr = w >> 1, wc = w & 1;
    const int m0 = blockIdx.y * 64;
    const int n0 = blockIdx.x * 128;

    f32x4 acc[2][4];
#pragma unroll
    for (int i = 0; i < 2; ++i)
#pragma unroll
        for (int j = 0; j < 4; ++j) acc[i][j] = (f32x4){0.f, 0.f, 0.f, 0.f};

    const int rowA = t >> 2;                 // [0,64)
    const int rowB1 = t >> 2;                // [0,64)
    const int rowB2 = (t + 256) >> 2;        // [64,128)
    const int koff = (t & 3) * 8;

#define GLDS(src, dst) __builtin_amdgcn_global_load_lds( \
        (const __attribute__((address_space(1))) void*)(src), \
        (__attribute__((address_space(3))) void*)(dst), 16, 0, 0)
#define STAGE(buf, k0) do { \
        GLDS(Ehi + (size_t)(m0 + rowA) * 256 + (k0) + koff, sAh[buf] + t * 8); \
        GLDS(Elo + (size_t)(m0 + rowA) * 256 + (k0) + koff, sAl[buf] + t * 8); \
        GLDS(S + (size_t)(n0 + rowB1) * 256 + (k0) + koff, sB[buf] + t * 8); \
        GLDS(S + (size_t)(n0 + rowB2) * 256 + (k0) + koff, sB[buf] + (t + 256) * 8); \
    } while (0)

    STAGE(0, 0);
    __syncthreads();
    int cur = 0;
    for (int k0 = 0; k0 < 256; k0 += 32) {
        if (k0 + 32 < 256) STAGE(cur ^ 1, k0 + 32);   // prefetch overlaps compute
        bf16x8 ah[2], al[2], b[4];
#pragma unroll
        for (int mi = 0; mi < 2; ++mi) {
            ah[mi] = *(const bf16x8*)(sAh[cur] + ((wr * 32 + mi * 16 + (lane & 15)) * 32 + (lane >> 4) * 8));
            al[mi] = *(const bf16x8*)(sAl[cur] + ((wr * 32 + mi * 16 + (lane & 15)) * 32 + (lane >> 4) * 8));
        }
#pragma unroll
        for (int ni = 0; ni < 4; ++ni)
            b[ni] = *(const bf16x8*)(sB[cur] + ((wc * 64 + ni * 16 + (lane & 15)) * 32 + (lane >> 4) * 8));
#pragma unroll
        for (int mi = 0; mi < 2; ++mi)
#pragma unroll
            for (int ni = 0; ni < 4; ++ni) {
                acc[mi][ni] = __builtin_amdgcn_mfma_f32_16x16x32_bf16(ah[mi], b[ni], acc[mi][ni], 0, 0, 0);
                acc[mi][ni] = __builtin_amdgcn_mfma_f32_16x16x32_bf16(al[mi], b[ni], acc[mi][ni], 0, 0, 0);
            }
        __syncthreads();
        cur ^= 1;
    }
#undef STAGE
#undef GLDS

    const int cr = (lane >> 4) * 4;   // C/D: col = lane&15, row = (lane>>4)*4 + reg  [m89-verified]
    const int cc = lane & 15;
#pragma unroll
    for (int mi = 0; mi < 2; ++mi)
#pragma unroll
        for (int ni = 0; ni < 4; ++ni)
#pragma unroll
            for (int reg = 0; reg < 4; ++reg)
                keys[(size_t)(m0 + wr * 32 + mi * 16 + cr + reg) * Rn + (n0 + wc * 64 + ni * 16 + cc)] =
                    acc[mi][ni][reg];
}

// One row/block, (512,8). f32-accurate keys: +-1-bin region, f64 exact rescore
// (direct rules read, ascending-d order) -> bitmap. Non-temporal output stores.
__global__ __launch_bounds__(NTH, 8) void select_kernel(
    const float* __restrict__ x,
    const float* __restrict__ centers,
    const float* __restrict__ widths,
    const float* __restrict__ keys,
    const int* __restrict__ rules,
    const float* __restrict__ cons_sum,
    float* __restrict__ out_rule,
    float* __restrict__ out_norm,
    float* __restrict__ out_mask)
{
    __shared__ float  s_x[Dn];
    __shared__ double s_e[256];            // 2KB  f64 table (boundary rescore only)
    __shared__ u32    s_hist[NBIN + 2];    // 4KB; becomes suffix array in place
    __shared__ u32    s_selmask[Rn / 32];  // 0.5KB selection bitmap
    __shared__ int    s_wtot[8];
    __shared__ float  s_wsum[8];
    __shared__ int    s_wpre[8];
    __shared__ int    s_cidx[CCAP];        // 1KB
    __shared__ double s_cval[CCAP];        // 2KB
    __shared__ int    s_selidx[Kn + 8];    // 1.6KB
    __shared__ float  s_selv[Kn + 8];      // 1.6KB
    __shared__ float  s_red[NTH];          // 2KB
    __shared__ int    s_bb, s_ccnt;

    const int t = threadIdx.x;
    const int lane = t & 63;
    const int w = t >> 6;
    const int b = blockIdx.x;

    // issue key loads first (independent of LDS)
    const f32x4* kptr = (const f32x4*)(keys + (size_t)b * Rn);
    f32x4 ka = kptr[t];
    f32x4 kb = kptr[NTH + t];

    if (t < Dn) s_x[t] = x[b * Dn + t];
    if (t == 0) { s_ccnt = 0; s_hist[NBIN] = 0u; s_hist[NBIN + 1] = 0u; }
    s_hist[t] = 0u;
    s_hist[t + NTH] = 0u;
    if (t < Rn / 32) s_selmask[t] = 0u;
    __syncthreads();

    // f64 single-dim table (bit-exact same math as all passing rounds)
    if (t < 256) {
        const int d = t >> 3;
        const double dx = (double)s_x[d] - (double)centers[t];
        const double ww = (double)widths[t];
        s_e[t] = -(dx * dx) / (2.0 * (ww * ww));
    }
    // histogram (8 atomics/thread, scattered bins)
    atomicAdd(&s_hist[binof(ka.x)], 1u);
    atomicAdd(&s_hist[binof(ka.y)], 1u);
    atomicAdd(&s_hist[binof(ka.z)], 1u);
    atomicAdd(&s_hist[binof(ka.w)], 1u);
    atomicAdd(&s_hist[binof(kb.x)], 1u);
    atomicAdd(&s_hist[binof(kb.y)], 1u);
    atomicAdd(&s_hist[binof(kb.z)], 1u);
    atomicAdd(&s_hist[binof(kb.w)], 1u);
    __syncthreads();

    // suffix scan over 1024 bins, written back in place: s_hist[k] := #keys in bins >= k
    const int h0 = (int)s_hist[2 * t];
    const int h1 = (int)s_hist[2 * t + 1];
    const int loc = h0 + h1;
    int S = loc;
#pragma unroll
    for (int off = 1; off < 64; off <<= 1) {
        const int vv = __shfl(S, lane + off < 64 ? lane + off : lane);
        if (lane + off < 64) S += vv;
    }
    if (lane == 0) s_wtot[w] = S;
    __syncthreads();
    int wsuf = 0;
#pragma unroll
    for (int ww = 0; ww < 8; ++ww) wsuf += (ww > w) ? s_wtot[ww] : 0;
    const int full = S + wsuf;          // suf(2t)
    s_hist[2 * t] = (u32)full;
    s_hist[2 * t + 1] = (u32)(full - h0);
    if (full - loc < Kn && full >= Kn) {
        s_bb = (full - h0 >= Kn) ? (2 * t + 1) : (2 * t);
    }
    __syncthreads();
    const int bb = s_bb;
    const int hi = (bb + 1 > NBIN - 1) ? NBIN - 1 : bb + 1;
    const int lo = (bb - 1 < 0) ? 0 : bb - 1;
    const int Acnt = (int)s_hist[hi + 1];   // keys in bins > hi: certainly top-K
    const int want_in = Kn - Acnt;

    // candidate append from registers (1 atomic + 1 store per hit)
#define CAND(kf, ridx) { const int bn = binof(kf); \
        if (bn >= lo && bn <= hi) { const int pos = atomicAdd(&s_ccnt, 1); \
            if (pos < CCAP) s_cidx[pos] = (ridx); } }
    CAND(ka.x, 4 * t + 0) CAND(ka.y, 4 * t + 1) CAND(ka.z, 4 * t + 2) CAND(ka.w, 4 * t + 3)
    CAND(kb.x, 2048 + 4 * t + 0) CAND(kb.y, 2048 + 4 * t + 1)
    CAND(kb.z, 2048 + 4 * t + 2) CAND(kb.w, 2048 + 4 * t + 3)
#undef CAND
    __syncthreads();
    const int cnt = s_ccnt < CCAP ? s_ccnt : CCAP;
    // convergent exact rescore straight from rules (ascending d = bit-exact order)
    if (t < cnt) {
        const int* rp = rules + s_cidx[t] * Dn;
        double s = 0.0;
#pragma unroll
        for (int d = 0; d < Dn; ++d) s += s_e[d * 8 + rp[d]];
        s_cval[t] = s;
    }
    __syncthreads();
    if (t < cnt) {
        const double mv = s_cval[t];
        const int mi = s_cidx[t];
        int rank = 0;
        for (int j = 0; j < cnt; ++j) {
            const double ov = s_cval[j];
            const int oi = s_cidx[j];
            rank += ((ov > mv) || (ov == mv && oi < mi)) ? 1 : 0;
        }
        if (rank < want_in) atomicOr(&s_selmask[mi >> 5], 1u << (mi & 31));
    }
    __syncthreads();

    // selection: overwrite key registers with firing value f (0 if unselected)
    u32 selbits = 0u;
    int cnt_sel = 0;
    float lsum = 0.f;
#define SEL(kf, ridx, bit) { const int bn = binof(kf); \
        bool sel = (bn > hi); \
        if (!sel && bn >= lo) sel = (s_selmask[(ridx) >> 5] >> ((ridx) & 31)) & 1u; \
        float f = 0.f; \
        if (sel) { f = expf(kf); selbits |= (1u << (bit)); ++cnt_sel; lsum += f; } \
        kf = f; }
    SEL(ka.x, 4 * t + 0, 0) SEL(ka.y, 4 * t + 1, 1) SEL(ka.z, 4 * t + 2, 2) SEL(ka.w, 4 * t + 3, 3)
    SEL(kb.x, 2048 + 4 * t + 0, 4) SEL(kb.y, 2048 + 4 * t + 1, 5)
    SEL(kb.z, 2048 + 4 * t + 2, 6) SEL(kb.w, 2048 + 4 * t + 3, 7)
#undef SEL
#pragma unroll
    for (int off = 32; off >= 1; off >>= 1) lsum += __shfl_xor(lsum, off);
    if (lane == 0) s_wsum[w] = lsum;
    int p = cnt_sel;
#pragma unroll
    for (int off = 1; off < 64; off <<= 1) {
        const int u = __shfl(p, lane >= off ? lane - off : lane);
        if (lane >= off) p += u;
    }
    if (lane == 63) s_wpre[w] = p;
    __syncthreads();
    float denom = 1e-9f;
#pragma unroll
    for (int ww = 0; ww < 8; ++ww) denom += s_wsum[ww];
    const float rinv = 1.0f / denom;
    int base = 0, nsel = 0;
#pragma unroll
    for (int ww = 0; ww < 8; ++ww) { base += (ww < w) ? s_wpre[ww] : 0; nsel += s_wpre[ww]; }
    int pos = base + (p - cnt_sel);

    // compaction (store raw f; scaled by rinv in matvec epilogue)
#define CPT(fv, ridx, bit) if ((selbits >> (bit)) & 1u) { s_selidx[pos] = (ridx); s_selv[pos] = fv; ++pos; }
    CPT(ka.x, 4 * t + 0, 0) CPT(ka.y, 4 * t + 1, 1) CPT(ka.z, 4 * t + 2, 2) CPT(ka.w, 4 * t + 3, 3)
    CPT(kb.x, 2048 + 4 * t + 0, 4) CPT(kb.y, 2048 + 4 * t + 1, 5)
    CPT(kb.z, 2048 + 4 * t + 2, 6) CPT(kb.w, 2048 + 4 * t + 3, 7)
#undef CPT

    // float4 norm/mask writes — non-temporal (never re-read on GPU)
    {
        f32x4* onorm = (f32x4*)(out_norm + (size_t)b * Rn);
        f32x4* omask = (f32x4*)(out_mask + (size_t)b * Rn);
        f32x4 nv, mk;
        nv.x = ka.x * rinv; mk.x = (selbits & 1u) ? 1.f : 0.f;
        nv.y = ka.y * rinv; mk.y = (selbits & 2u) ? 1.f : 0.f;
        nv.z = ka.z * rinv; mk.z = (selbits & 4u) ? 1.f : 0.f;
        nv.w = ka.w * rinv; mk.w = (selbits & 8u) ? 1.f : 0.f;
        __builtin_nontemporal_store(nv, &onorm[t]);
        __builtin_nontemporal_store(mk, &omask[t]);
        nv.x = kb.x * rinv; mk.x = (selbits & 16u) ? 1.f : 0.f;
        nv.y = kb.y * rinv; mk.y = (selbits & 32u) ? 1.f : 0.f;
        nv.z = kb.z * rinv; mk.z = (selbits & 64u) ? 1.f : 0.f;
        nv.w = kb.w * rinv; mk.w = (selbits & 128u) ? 1.f : 0.f;
        __builtin_nontemporal_store(nv, &onorm[NTH + t]);
        __builtin_nontemporal_store(mk, &omask[NTH + t]);
    }
    __syncthreads();

    // sparse matvec over compacted list
    const int g = t >> 5;
    const int c = t & 31;
    float acc = 0.f;
    for (int i = g; i < nsel; i += 16) {
        acc += s_selv[i] * cons_sum[s_selidx[i] * Cn + c];
    }
    s_red[t] = acc;
    __syncthreads();
    if (t < Cn) {
        float ss = 0.f;
#pragma unroll
        for (int gg = 0; gg < 16; ++gg) ss += s_red[gg * 32 + t];
        float xs = 1.f;
#pragma unroll
        for (int d = 0; d < Dn; ++d) xs += s_x[d];
        __builtin_nontemporal_store(xs * ss * rinv, &out_rule[(size_t)b * Cn + t]);
    }
}

extern "C" void kernel_launch(void* const* d_in, const int* in_sizes, int n_in,
                              void* d_out, int out_size, void* d_ws, size_t ws_size,
                              hipStream_t stream) {
    (void)in_sizes; (void)n_in; (void)out_size; (void)ws_size;
    const float* x = (const float*)d_in[0];
    const float* centers = (const float*)d_in[1];
    const float* widths = (const float*)d_in[2];
    const float* consequents = (const float*)d_in[3];
    const int* rules = (const int*)d_in[4];

    float* out_rule = (float*)d_out;                       // B*C
    float* out_norm = out_rule + (size_t)Bn * Cn;          // B*R
    float* out_mask = out_norm + (size_t)Bn * Rn;          // B*R

    char* wsb = (char*)d_ws;
    float* cons_sum = (float*)wsb;                         // 512KB @ 0
    u16*   Smat  = (u16*)(wsb + (512 << 10));              // 2MB   @ 512K
    u16*   Ehi   = (u16*)(wsb + (2560 << 10));             // 512KB @ 2560K
    u16*   Elo   = (u16*)(wsb + (3072 << 10));             // 512KB @ 3072K
    float* keys  = (float*)(wsb + (3584 << 10));           // 16MB  @ 3584K

    prep_kernel<<<1152, 256, 0, stream>>>(x, centers, widths, consequents, rules,
                                          cons_sum, (uint4*)Smat, (uint4*)Ehi, (uint4*)Elo);
    dim3 gg(Rn / 128, Bn / 64);   // 32 x 16 = 512 blocks (2/CU)
    key_gemm_kernel<<<gg, 256, 0, stream>>>(Ehi, Elo, Smat, keys);
    select_kernel<<<Bn, NTH, 0, stream>>>(x, centers, widths, keys, rules, cons_sum,
                                          out_rule, out_norm, out_mask);
}